// Round 12
// baseline (468.989 us; speedup 1.0000x reference)
//
#include <hip/hip_runtime.h>
#include <stdint.h>

#define NN 50000
#define NE 800000
#define LN_EPS 1e-5f
#define NBLK 196  // ceil(NN/256)

typedef __attribute__((ext_vector_type(8))) __bf16 bf16x8;
typedef __attribute__((ext_vector_type(4))) float floatx4;
typedef __attribute__((ext_vector_type(2))) float floatx2;

#define GLD_LDS16(gp, lp)                                              \
  __builtin_amdgcn_global_load_lds(                                    \
      (const __attribute__((address_space(1))) unsigned int*)(gp),     \
      (__attribute__((address_space(3))) unsigned int*)(lp), 16, 0, 0)

__device__ __forceinline__ float bfbits2f(unsigned short u) {
  return __uint_as_float(((unsigned)u) << 16);
}
__device__ __forceinline__ unsigned short f2bfbits(float f) {
  unsigned u = __float_as_uint(f);
  u += 0x7FFFu + ((u >> 16) & 1u);   // round-to-nearest-even
  return (unsigned short)(u >> 16);
}
__device__ __forceinline__ unsigned char f2fp8(float f) {
  unsigned p = __builtin_amdgcn_cvt_pk_fp8_f32(f, f, 0, false);
  return (unsigned char)(p & 0xff);
}
// accumulate 16 fp8 (one uint4) into a[16] via HW cvt (2 elems/inst)
__device__ __forceinline__ void accf8(float* a, uint4 r) {
  const unsigned* u = &r.x;
#pragma unroll
  for (int k = 0; k < 4; ++k) {
    floatx2 lo = __builtin_amdgcn_cvt_pk_f32_fp8(u[k], false);
    floatx2 hi = __builtin_amdgcn_cvt_pk_f32_fp8(u[k], true);
    a[4 * k + 0] += lo[0]; a[4 * k + 1] += lo[1];
    a[4 * k + 2] += hi[0]; a[4 * k + 3] += hi[1];
  }
}
__device__ __forceinline__ float4 ld4f(const void* p, size_t i, bool f32) {
  if (f32) return *reinterpret_cast<const float4*>((const float*)p + i);
  ushort4 r = *reinterpret_cast<const ushort4*>((const unsigned short*)p + i);
  return make_float4(bfbits2f(r.x), bfbits2f(r.y), bfbits2f(r.z), bfbits2f(r.w));
}
__device__ __forceinline__ float ld1f(const void* p, size_t i, bool f32) {
  return f32 ? ((const float*)p)[i] : bfbits2f(((const unsigned short*)p)[i]);
}

// merged prep kernel.
//  block 0        : dtype detect (feat) -> flag
//  blocks 1..80   : weight transpose tiles (self-detecting dtype per-W)
//  blocks 81..3205: edge count atomics
__global__ __launch_bounds__(256) void prep_kernel(
    const void* __restrict__ feat, int* __restrict__ flag,
    const void* __restrict__ ws0, const void* __restrict__ wn0,
    const void* __restrict__ ws1, const void* __restrict__ wn1,
    const void* __restrict__ ws2, const void* __restrict__ wn2,
    unsigned short* __restrict__ Bt0,
    const int* __restrict__ dst, int* __restrict__ counts) {
  const int b = blockIdx.x;
  const int tid = threadIdx.x;
  if (b == 0) {
    if (tid < 64) {
      int cnt = 0;
      const unsigned short* u = (const unsigned short*)feat;
      for (int i = tid; i < 512; i += 64) {
        float v = bfbits2f(u[i]);
        if (!(fabsf(v) < 1e6f)) cnt++;
      }
#pragma unroll
      for (int off = 32; off > 0; off >>= 1) cnt += __shfl_down(cnt, off, 64);
      if (tid == 0) flag[0] = (cnt > 8) ? 1 : 0;
    }
    return;
  }
  if (b <= 80) {
    __shared__ float sm[64][65];
    __shared__ int wcnt;
    int tile = b - 1;  // 0..79
    const void* W;
    int D, nbase, local;
    if (tile < 16)      { W = ws0; D = 256; nbase = 0;    local = tile; }
    else if (tile < 32) { W = wn0; D = 256; nbase = 256;  local = tile - 16; }
    else if (tile < 48) { W = ws1; D = 256; nbase = 512;  local = tile - 32; }
    else if (tile < 64) { W = wn1; D = 256; nbase = 768;  local = tile - 48; }
    else if (tile < 72) { W = ws2; D = 128; nbase = 1024; local = tile - 64; }
    else                { W = wn2; D = 128; nbase = 1152; local = tile - 72; }
    if (tid == 0) wcnt = 0;
    __syncthreads();
    {
      const unsigned short* wu = (const unsigned short*)W;
      int c = 0;
#pragma unroll
      for (int r = 0; r < 2; ++r) {
        float v = bfbits2f(wu[tid + r * 256]);
        if (!(fabsf(v) < 1e6f)) c++;
      }
      if (c) atomicAdd(&wcnt, c);
    }
    __syncthreads();
    bool f32 = wcnt > 8;
    int nt = local >> 2, kt = local & 3;
    int n0 = nt * 64, k0 = kt * 64;
    int lr = tid >> 4;        // 0..15
    int lc = (tid & 15) * 4;  // 0..60
#pragma unroll
    for (int r = 0; r < 4; ++r) {
      int kl = r * 16 + lr;
      float4 v = ld4f(W, (size_t)(k0 + kl) * D + n0 + lc, f32);
      sm[lc + 0][kl] = v.x;
      sm[lc + 1][kl] = v.y;
      sm[lc + 2][kl] = v.z;
      sm[lc + 3][kl] = v.w;
    }
    __syncthreads();
#pragma unroll
    for (int r = 0; r < 4; ++r) {
      int nl = r * 16 + lr;
      ushort4 o = {f2bfbits(sm[nl][lc]), f2bfbits(sm[nl][lc + 1]),
                   f2bfbits(sm[nl][lc + 2]), f2bfbits(sm[nl][lc + 3])};
      *reinterpret_cast<ushort4*>(Bt0 + (size_t)(nbase + n0 + nl) * 256 + k0 + lc) = o;
    }
    return;
  }
  int e = (b - 81) * 256 + tid;
  if (e < NE) atomicAdd(&counts[dst[e]], 1);
}

__global__ __launch_bounds__(256) void bsum_kernel(const int* __restrict__ counts,
                                                   int* __restrict__ bsum) {
  int i = blockIdx.x * 256 + threadIdx.x;
  int v = (i < NN) ? counts[i] : 0;
#pragma unroll
  for (int off = 32; off > 0; off >>= 1) v += __shfl_down(v, off, 64);
  __shared__ int w[4];
  if ((threadIdx.x & 63) == 0) w[threadIdx.x >> 6] = v;
  __syncthreads();
  if (threadIdx.x == 0) bsum[blockIdx.x] = w[0] + w[1] + w[2] + w[3];
}

// folds bscan into rowptr — each block tree-reduces bsum[0..blockIdx).
__global__ __launch_bounds__(256) void rowptr_kernel(const int* __restrict__ counts,
                                                     const int* __restrict__ bsum,
                                                     int* __restrict__ rowptr,
                                                     int* __restrict__ cursor) {
  __shared__ int sh[256];
  int tid = threadIdx.x;
  int v0 = (tid < blockIdx.x) ? bsum[tid] : 0;  // NBLK=196 <= 256
  sh[tid] = v0;
  __syncthreads();
#pragma unroll
  for (int off = 128; off > 0; off >>= 1) {
    if (tid < off) sh[tid] += sh[tid + off];
    __syncthreads();
  }
  int base = sh[0];
  __syncthreads();
  int i = blockIdx.x * 256 + tid;
  int v = (i < NN) ? counts[i] : 0;
  sh[tid] = v;
  __syncthreads();
  for (int off = 1; off < 256; off <<= 1) {
    int t = (tid >= off) ? sh[tid - off] : 0;
    __syncthreads();
    sh[tid] += t;
    __syncthreads();
  }
  int incl = sh[tid];
  if (i < NN) {
    int r = base + incl - v;
    rowptr[i] = r;
    cursor[i] = r;
  }
  if (i == NN - 1) rowptr[NN] = base + incl;
}

__global__ void fill_kernel(const int* __restrict__ src, const int* __restrict__ dst,
                            int* __restrict__ cursor, int* __restrict__ csr_src) {
  int e = blockIdx.x * blockDim.x + threadIdx.x;
  if (e >= NE) return;
  int pos = atomicAdd(&cursor[dst[e]], 1);
  csr_src[pos] = src[e];
}

// ---- MFMA GEMM: Yself(bf16)=A@Ws+bias, Yn(fp8)=A@Wn ----
// Proven R17 config (450.4us): BK=32, __syncthreads skeleton, coalesced
// LDS-restaged epilogue, 1-D XCD grid, fused fp32-A path for layer 0.
template <int TWO_D, bool MAYF32>
__global__ __launch_bounds__(256) void gemm_pack_kernel(
    const unsigned short* __restrict__ A0, const float* __restrict__ A1f,
    const unsigned short* __restrict__ Bt,
    const void* __restrict__ bias, unsigned short* __restrict__ Yself,
    unsigned char* __restrict__ Yn, const int* __restrict__ dtflag) {
  constexpr int D = TWO_D / 2;
  constexpr int NC = TWO_D / 128;  // col-blocks per row-panel
  __shared__ unsigned short LDS[16384];  // 32 KB; epilogue reuses all

  const int id = blockIdx.x;
  const int sup = id >> 3;
  const int rb = (id & 7) + 8 * (sup / NC);
  const int row0 = rb * 128;
  if (row0 >= NN) return;  // padded grid; block-uniform exit before barriers
  const int col0 = (sup & (NC - 1)) * 128;
  const bool self = col0 < D;  // block-uniform

  bool inf32 = dtflag[0] != 0;
  const bool af32 = MAYF32 && inf32;

  const int tid = threadIdx.x;
  const int lane = tid & 63;
  const int wave = tid >> 6;
  const int wr = (wave >> 1) * 64;
  const int wc = (wave & 1) * 64;
  const int fr = lane & 15;
  const int q = lane >> 4;
  const int sw = (q ^ ((fr >> 1) & 3)) * 8;

  floatx4 acc[4][4];
#pragma unroll
  for (int i = 0; i < 4; ++i)
#pragma unroll
    for (int j = 0; j < 4; ++j) acc[i][j] = (floatx4){0.f, 0.f, 0.f, 0.f};

  const int srow = tid >> 2;
  const int gch = ((tid & 3) ^ ((tid >> 3) & 3)) * 8;
  int ar0 = row0 + srow;      if (ar0 >= NN) ar0 = NN - 1;
  int ar1 = row0 + srow + 64; if (ar1 >= NN) ar1 = NN - 1;
  const size_t ga0 = (size_t)ar0 * 256 + gch;
  const size_t ga1 = (size_t)ar1 * 256 + gch;
  const size_t gb0 = (size_t)(col0 + srow) * 256 + gch;
  const size_t gb1 = (size_t)(col0 + srow + 64) * 256 + gch;
  const int lo0 = (tid & 192) * 8;  // wave-uniform LDS base
  unsigned short* la0 = LDS + lo0;
  unsigned short* la1 = LDS + lo0 + 2048;
  unsigned short* lb0 = LDS + 8192 + lo0;
  unsigned short* lb1 = LDS + 8192 + lo0 + 2048;

  const int arow = tid >> 3;                              // 0..31
  const int ag = ((tid & 7) ^ ((tid >> 3) & 7)) * 4;      // f32 col offset
  size_t gaf[4];
  if (MAYF32) {
#pragma unroll
    for (int m = 0; m < 4; ++m) {
      int r = row0 + 32 * m + arow;
      if (r >= NN) r = NN - 1;
      gaf[m] = (size_t)r * 256 + ag;
    }
  }

  for (int kb = 0; kb < 256; kb += 32) {
    if (kb) __syncthreads();  // WAR: all reads of prior step done
    if (af32) {
#pragma unroll
      for (int m = 0; m < 4; ++m)
        GLD_LDS16(A1f + gaf[m] + kb, LDS + m * 2048 + lo0);
    } else {
      GLD_LDS16(A0 + ga0 + kb, la0);
      GLD_LDS16(A0 + ga1 + kb, la1);
    }
    GLD_LDS16(Bt + gb0 + kb, lb0);
    GLD_LDS16(Bt + gb1 + kb, lb1);
    __syncthreads();          // full fence + vmcnt drain: staging visible
    bf16x8 af[4], bfr[4];
    if (af32) {
      const float* Af = (const float*)LDS;
#pragma unroll
      for (int i = 0; i < 4; ++i) {
        int r = wr + i * 16 + fr;
        int c0 = (q * 2) ^ (r & 7);
        float4 f0 = *reinterpret_cast<const float4*>(Af + r * 32 + c0 * 4);
        float4 f1 = *reinterpret_cast<const float4*>(Af + r * 32 + (c0 ^ 1) * 4);
        bf16x8 v;
        v[0] = (__bf16)f0.x; v[1] = (__bf16)f0.y; v[2] = (__bf16)f0.z; v[3] = (__bf16)f0.w;
        v[4] = (__bf16)f1.x; v[5] = (__bf16)f1.y; v[6] = (__bf16)f1.z; v[7] = (__bf16)f1.w;
        af[i] = v;
      }
    } else {
      const unsigned short* Ap = LDS;
#pragma unroll
      for (int i = 0; i < 4; ++i)
        af[i] = *reinterpret_cast<const bf16x8*>(Ap + (wr + i * 16 + fr) * 32 + sw);
    }
    const unsigned short* Bp = LDS + 8192;
#pragma unroll
    for (int j = 0; j < 4; ++j)
      bfr[j] = *reinterpret_cast<const bf16x8*>(Bp + (wc + j * 16 + fr) * 32 + sw);
#pragma unroll
    for (int i = 0; i < 4; ++i)
#pragma unroll
      for (int j = 0; j < 4; ++j)
        acc[i][j] = __builtin_amdgcn_mfma_f32_16x16x32_bf16(af[i], bfr[j], acc[i][j], 0, 0, 0);
  }
  __syncthreads();  // WAR: all K-loop LDS reads done before epilogue scatter

  // ---- epilogue: scatter acc -> LDS tile, then coalesced flush ----
  if (self) {
    unsigned short* T = LDS;  // [128][128] bf16, 32 KB
#pragma unroll
    for (int j = 0; j < 4; ++j) {
      int cl = wc + j * 16 + fr;  // 0..127
      float bj = ld1f(bias, col0 + cl, inf32);
#pragma unroll
      for (int i = 0; i < 4; ++i) {
        int rbase = wr + i * 16 + q * 4;
#pragma unroll
        for (int r = 0; r < 4; ++r)
          T[(rbase + r) * 128 + cl] = f2bfbits(acc[i][j][r] + bj);
      }
    }
    __syncthreads();
    const char* lp = (const char*)LDS;
    char* gp0 = (char*)Yself;
#pragma unroll
    for (int it = 0; it < 8; ++it) {
      int cb = (tid + it * 256) * 16;   // byte index in tile
      int tr = cb >> 8;                 // tile row (256 B rows)
      int cob = cb & 255;
      if (row0 + tr < NN) {
        uint4 v = *reinterpret_cast<const uint4*>(lp + cb);
        *reinterpret_cast<uint4*>(gp0 + (size_t)(row0 + tr) * (D * 2) + col0 * 2 + cob) = v;
      }
    }
  } else {
    unsigned char* T = (unsigned char*)LDS;  // [128][128] fp8, 16 KB
#pragma unroll
    for (int j = 0; j < 4; ++j) {
      int cl = wc + j * 16 + fr;
#pragma unroll
      for (int i = 0; i < 4; ++i) {
        int rbase = wr + i * 16 + q * 4;
#pragma unroll
        for (int r = 0; r < 4; ++r)
          T[(rbase + r) * 128 + cl] = f2fp8(acc[i][j][r]);
      }
    }
    __syncthreads();
    const char* lp = (const char*)LDS;
    char* gp0 = (char*)Yn;
#pragma unroll
    for (int it = 0; it < 4; ++it) {
      int cb = (tid + it * 256) * 16;
      int tr = cb >> 7;                 // tile row (128 B rows)
      int cob = cb & 127;
      if (row0 + tr < NN) {
        uint4 v = *reinterpret_cast<const uint4*>(lp + cb);
        *reinterpret_cast<uint4*>(gp0 + (size_t)(row0 + tr) * D + (col0 - D) + cob) = v;
      }
    }
  }
}

// ---- fused: h = ReLU(LN(Yself + mean(Yn[nbrs]))), D=256 ----
// At its compulsory-traffic floor (R8-R10: FETCH invariant 94MB; per-XCD
// compulsory = 8 x 63% x 12.8MB = 65MB Yn re-fetch, matches).
// rowbase: both layers run as halves so no ln dispatch exceeds ~42us —
// frees the (replay-dominated) top-5 to reveal the next-largest kernel.
__global__ __launch_bounds__(256) void fused_ln_kernel(
    const unsigned char* __restrict__ Yn, const unsigned short* __restrict__ Yself,
    const int* __restrict__ rowptr, const int* __restrict__ csr_src,
    const void* __restrict__ indeg, const void* __restrict__ g,
    const void* __restrict__ be, unsigned short* __restrict__ out,
    const int* __restrict__ dtflag, int rowbase) {
  bool inf32 = dtflag[0] != 0;
  int row = rowbase + blockIdx.x * 4 + (threadIdx.x >> 6);
  int lane = threadIdx.x & 63;
  int qq = lane >> 4;
  int l16 = lane & 15;
  int beg = rowptr[row], end = rowptr[row + 1];
  float a[16] = {};
  int e = beg + qq;
  for (; e + 4 < end; e += 8) {
    int s0 = csr_src[e], s1 = csr_src[e + 4];
    uint4 r0 = *reinterpret_cast<const uint4*>(Yn + (size_t)s0 * 256 + l16 * 16);
    uint4 r1 = *reinterpret_cast<const uint4*>(Yn + (size_t)s1 * 256 + l16 * 16);
    accf8(a, r0); accf8(a, r1);
  }
  if (e < end) {
    uint4 r0 = *reinterpret_cast<const uint4*>(Yn + (size_t)csr_src[e] * 256 + l16 * 16);
    accf8(a, r0);
  }
#pragma unroll
  for (int k = 0; k < 16; ++k) {
    a[k] += __shfl_xor(a[k], 16, 64);
    a[k] += __shfl_xor(a[k], 32, 64);
  }
  float rd = 1.0f / ld1f(indeg, row, inf32);
  uint4 ys0 = *reinterpret_cast<const uint4*>(Yself + (size_t)row * 256 + l16 * 16);
  uint4 ys1 = *reinterpret_cast<const uint4*>(Yself + (size_t)row * 256 + l16 * 16 + 8);
  const unsigned* y0 = &ys0.x;
  const unsigned* y1 = &ys1.x;
  float vals[16];
#pragma unroll
  for (int k = 0; k < 4; ++k) {
    vals[2 * k] = a[2 * k] * rd + bfbits2f((unsigned short)(y0[k] & 0xffff));
    vals[2 * k + 1] = a[2 * k + 1] * rd + bfbits2f((unsigned short)(y0[k] >> 16));
    vals[8 + 2 * k] = a[8 + 2 * k] * rd + bfbits2f((unsigned short)(y1[k] & 0xffff));
    vals[9 + 2 * k] = a[9 + 2 * k] * rd + bfbits2f((unsigned short)(y1[k] >> 16));
  }
  float s = 0.f, sq = 0.f;
#pragma unroll
  for (int k = 0; k < 16; ++k) { s += vals[k]; sq += vals[k] * vals[k]; }
#pragma unroll
  for (int off = 1; off < 16; off <<= 1) {
    s += __shfl_xor(s, off, 64);
    sq += __shfl_xor(sq, off, 64);
  }
  float mu = s * (1.0f / 256.0f);
  float var = fmaxf(sq * (1.0f / 256.0f) - mu * mu, 0.0f);
  float rs = rsqrtf(var + LN_EPS);
  if (qq == 0) {
    uint4 o0, o1;
    unsigned* u0 = &o0.x;
    unsigned* u1 = &o1.x;
#pragma unroll
    for (int k = 0; k < 4; ++k) {
      int c = l16 * 16 + 2 * k;
      float x0 = (vals[2 * k] - mu) * rs * ld1f(g, c, inf32) + ld1f(be, c, inf32);
      float x1 = (vals[2 * k + 1] - mu) * rs * ld1f(g, c + 1, inf32) + ld1f(be, c + 1, inf32);
      float x2 = (vals[8 + 2 * k] - mu) * rs * ld1f(g, c + 8, inf32) + ld1f(be, c + 8, inf32);
      float x3 = (vals[9 + 2 * k] - mu) * rs * ld1f(g, c + 9, inf32) + ld1f(be, c + 9, inf32);
      u0[k] = (unsigned)f2bfbits(fmaxf(x0, 0.f)) | ((unsigned)f2bfbits(fmaxf(x1, 0.f)) << 16);
      u1[k] = (unsigned)f2bfbits(fmaxf(x2, 0.f)) | ((unsigned)f2bfbits(fmaxf(x3, 0.f)) << 16);
    }
    *reinterpret_cast<uint4*>(out + (size_t)row * 256 + l16 * 16) = o0;
    *reinterpret_cast<uint4*>(out + (size_t)row * 256 + l16 * 16 + 8) = o1;
  }
}

// ---- fused final: d_out = Yself + mean(Yn[nbrs]); D=128 ----
__global__ __launch_bounds__(256) void fused_out_kernel(
    const unsigned char* __restrict__ Yn, const unsigned short* __restrict__ Yself,
    const int* __restrict__ rowptr, const int* __restrict__ csr_src,
    const void* __restrict__ indeg, void* __restrict__ out,
    const int* __restrict__ dtflag) {
  bool inf32 = dtflag[0] != 0;
  int row = blockIdx.x * 4 + (threadIdx.x >> 6);
  int lane = threadIdx.x & 63;
  int oo = lane >> 3;   // 0..7
  int l8 = lane & 7;
  int beg = rowptr[row], end = rowptr[row + 1];
  float a[16] = {};
  int e = beg + oo;
  for (; e + 8 < end; e += 16) {
    int s0 = csr_src[e], s1 = csr_src[e + 8];
    uint4 r0 = *reinterpret_cast<const uint4*>(Yn + (size_t)s0 * 128 + l8 * 16);
    uint4 r1 = *reinterpret_cast<const uint4*>(Yn + (size_t)s1 * 128 + l8 * 16);
    accf8(a, r0); accf8(a, r1);
  }
  if (e < end) {
    uint4 r0 = *reinterpret_cast<const uint4*>(Yn + (size_t)csr_src[e] * 128 + l8 * 16);
    accf8(a, r0);
  }
#pragma unroll
  for (int k = 0; k < 16; ++k) {
    a[k] += __shfl_xor(a[k], 8, 64);
    a[k] += __shfl_xor(a[k], 16, 64);
    a[k] += __shfl_xor(a[k], 32, 64);
  }
  if (oo == 0) {
    float rd = 1.0f / ld1f(indeg, row, inf32);
    uint4 ys0 = *reinterpret_cast<const uint4*>(Yself + (size_t)row * 128 + l8 * 16);
    uint4 ys1 = *reinterpret_cast<const uint4*>(Yself + (size_t)row * 128 + l8 * 16 + 8);
    const unsigned* y0 = &ys0.x;
    const unsigned* y1 = &ys1.x;
    float v[16];
#pragma unroll
    for (int k = 0; k < 4; ++k) {
      v[2 * k] = a[2 * k] * rd + bfbits2f((unsigned short)(y0[k] & 0xffff));
      v[2 * k + 1] = a[2 * k + 1] * rd + bfbits2f((unsigned short)(y0[k] >> 16));
      v[8 + 2 * k] = a[8 + 2 * k] * rd + bfbits2f((unsigned short)(y1[k] & 0xffff));
      v[9 + 2 * k] = a[9 + 2 * k] * rd + bfbits2f((unsigned short)(y1[k] >> 16));
    }
    size_t base = (size_t)row * 128 + l8 * 16;
    if (inf32) {
#pragma unroll
      for (int p = 0; p < 4; ++p) {
        float4 o = {v[4 * p], v[4 * p + 1], v[4 * p + 2], v[4 * p + 3]};
        *reinterpret_cast<float4*>((float*)out + base + 4 * p) = o;
      }
    } else {
      uint4 o0, o1;
      unsigned* u0 = &o0.x;
      unsigned* u1 = &o1.x;
#pragma unroll
      for (int k = 0; k < 4; ++k) {
        u0[k] = (unsigned)f2bfbits(v[2 * k]) | ((unsigned)f2bfbits(v[2 * k + 1]) << 16);
        u1[k] = (unsigned)f2bfbits(v[8 + 2 * k]) | ((unsigned)f2bfbits(v[9 + 2 * k]) << 16);
      }
      *reinterpret_cast<uint4*>((unsigned short*)out + base) = o0;
      *reinterpret_cast<uint4*>((unsigned short*)out + base + 8) = o1;
    }
  }
}

extern "C" void kernel_launch(void* const* d_in, const int* in_sizes, int n_in,
                              void* d_out, int out_size, void* d_ws, size_t ws_size,
                              hipStream_t stream) {
  const void* feat = d_in[0];
  const int* ei = (const int*)d_in[1];
  const void* indeg = d_in[2];
  const void* ws0 = d_in[3]; const void* wn0 = d_in[4]; const void* b0 = d_in[5];
  const void* ws1 = d_in[6]; const void* wn1 = d_in[7]; const void* b1 = d_in[8];
  const void* ws2 = d_in[9]; const void* wn2 = d_in[10]; const void* b2 = d_in[11];
  const void* g0 = d_in[12]; const void* be0 = d_in[13];
  const void* g1 = d_in[14]; const void* be1 = d_in[15];
  const int* src = ei;
  const int* dst = ei + NE;

  unsigned short* featbf = (unsigned short*)d_ws;            // 25.6 MB (spare)
  unsigned short* hbf = featbf + (size_t)NN * 256;           // 25.6 MB
  unsigned short* Yself = hbf + (size_t)NN * 256;            // 25.6 MB bf16 [NN][256]
  unsigned char* Yn = (unsigned char*)(Yself + (size_t)NN * 256);  // 12.8 MB fp8 [NN][256]
  unsigned short* Bt0 = (unsigned short*)(Yn + (size_t)NN * 256);
  unsigned short* Bt1 = Bt0 + 512 * 256;
  unsigned short* Bt2 = Bt1 + 512 * 256;
  int* flag = (int*)(Bt2 + 256 * 256);
  int* bsum = flag + 4;
  int* counts = bsum + 256;
  int* rowptr = counts + NN;
  int* cursor = rowptr + NN + 1;
  int* csr_src = cursor + NN;

  dim3 blk(256);
  dim3 gE((NE + 255) / 256);
  dim3 gRow(12500);
  dim3 gHalf(6250);

  hipMemsetAsync(counts, 0, NN * sizeof(int), stream);
  prep_kernel<<<3206, blk, 0, stream>>>(feat, flag, ws0, wn0, ws1, wn1, ws2, wn2,
                                        Bt0, dst, counts);
  bsum_kernel<<<NBLK, blk, 0, stream>>>(counts, bsum);
  rowptr_kernel<<<NBLK, blk, 0, stream>>>(counts, bsum, rowptr, cursor);
  fill_kernel<<<gE, blk, 0, stream>>>(src, dst, cursor, csr_src);

  // layer 0 (fused fp32 path if flag==1); ln as halves (telemetry)
  gemm_pack_kernel<512, true><<<dim3(392 * 4), blk, 0, stream>>>(
      (const unsigned short*)feat, (const float*)feat, Bt0, b0, Yself, Yn, flag);
  fused_ln_kernel<<<gHalf, blk, 0, stream>>>(Yn, Yself, rowptr, csr_src, indeg, g0, be0, hbf, flag, 0);
  fused_ln_kernel<<<gHalf, blk, 0, stream>>>(Yn, Yself, rowptr, csr_src, indeg, g0, be0, hbf, flag, 25000);
  // layer 1; ln as halves
  gemm_pack_kernel<512, false><<<dim3(392 * 4), blk, 0, stream>>>(
      hbf, nullptr, Bt1, b1, Yself, Yn, flag);
  fused_ln_kernel<<<gHalf, blk, 0, stream>>>(Yn, Yself, rowptr, csr_src, indeg, g1, be1, hbf, flag, 0);
  fused_ln_kernel<<<gHalf, blk, 0, stream>>>(Yn, Yself, rowptr, csr_src, indeg, g1, be1, hbf, flag, 25000);
  // layer 2 -> d_out
  gemm_pack_kernel<256, false><<<dim3(392 * 2), blk, 0, stream>>>(
      hbf, nullptr, Bt2, b2, Yself, Yn, flag);
  fused_out_kernel<<<gRow, blk, 0, stream>>>(Yn, Yself, rowptr, csr_src, indeg, d_out, flag);
}

// Round 13
// 447.068 us; speedup vs baseline: 1.0490x; 1.0490x over previous
//
#include <hip/hip_runtime.h>
#include <stdint.h>

#define NN 50000
#define NE 800000
#define LN_EPS 1e-5f
#define NBLK 196  // ceil(NN/256)
#define FRNG 6250  // fill: rows per XCD-range

typedef __attribute__((ext_vector_type(8))) __bf16 bf16x8;
typedef __attribute__((ext_vector_type(4))) float floatx4;
typedef __attribute__((ext_vector_type(2))) float floatx2;

#define GLD_LDS16(gp, lp)                                              \
  __builtin_amdgcn_global_load_lds(                                    \
      (const __attribute__((address_space(1))) unsigned int*)(gp),     \
      (__attribute__((address_space(3))) unsigned int*)(lp), 16, 0, 0)

__device__ __forceinline__ float bfbits2f(unsigned short u) {
  return __uint_as_float(((unsigned)u) << 16);
}
__device__ __forceinline__ unsigned short f2bfbits(float f) {
  unsigned u = __float_as_uint(f);
  u += 0x7FFFu + ((u >> 16) & 1u);   // round-to-nearest-even
  return (unsigned short)(u >> 16);
}
__device__ __forceinline__ unsigned char f2fp8(float f) {
  unsigned p = __builtin_amdgcn_cvt_pk_fp8_f32(f, f, 0, false);
  return (unsigned char)(p & 0xff);
}
// accumulate 16 fp8 (one uint4) into a[16] via HW cvt (2 elems/inst)
__device__ __forceinline__ void accf8(float* a, uint4 r) {
  const unsigned* u = &r.x;
#pragma unroll
  for (int k = 0; k < 4; ++k) {
    floatx2 lo = __builtin_amdgcn_cvt_pk_f32_fp8(u[k], false);
    floatx2 hi = __builtin_amdgcn_cvt_pk_f32_fp8(u[k], true);
    a[4 * k + 0] += lo[0]; a[4 * k + 1] += lo[1];
    a[4 * k + 2] += hi[0]; a[4 * k + 3] += hi[1];
  }
}
__device__ __forceinline__ float4 ld4f(const void* p, size_t i, bool f32) {
  if (f32) return *reinterpret_cast<const float4*>((const float*)p + i);
  ushort4 r = *reinterpret_cast<const ushort4*>((const unsigned short*)p + i);
  return make_float4(bfbits2f(r.x), bfbits2f(r.y), bfbits2f(r.z), bfbits2f(r.w));
}
__device__ __forceinline__ float ld1f(const void* p, size_t i, bool f32) {
  return f32 ? ((const float*)p)[i] : bfbits2f(((const unsigned short*)p)[i]);
}

// merged prep kernel.
//  block 0        : dtype detect (feat) -> flag
//  blocks 1..80   : weight transpose tiles (self-detecting dtype per-W)
//  blocks 81..3205: edge count atomics
__global__ __launch_bounds__(256) void prep_kernel(
    const void* __restrict__ feat, int* __restrict__ flag,
    const void* __restrict__ ws0, const void* __restrict__ wn0,
    const void* __restrict__ ws1, const void* __restrict__ wn1,
    const void* __restrict__ ws2, const void* __restrict__ wn2,
    unsigned short* __restrict__ Bt0,
    const int* __restrict__ dst, int* __restrict__ counts) {
  const int b = blockIdx.x;
  const int tid = threadIdx.x;
  if (b == 0) {
    if (tid < 64) {
      int cnt = 0;
      const unsigned short* u = (const unsigned short*)feat;
      for (int i = tid; i < 512; i += 64) {
        float v = bfbits2f(u[i]);
        if (!(fabsf(v) < 1e6f)) cnt++;
      }
#pragma unroll
      for (int off = 32; off > 0; off >>= 1) cnt += __shfl_down(cnt, off, 64);
      if (tid == 0) flag[0] = (cnt > 8) ? 1 : 0;
    }
    return;
  }
  if (b <= 80) {
    __shared__ float sm[64][65];
    __shared__ int wcnt;
    int tile = b - 1;  // 0..79
    const void* W;
    int D, nbase, local;
    if (tile < 16)      { W = ws0; D = 256; nbase = 0;    local = tile; }
    else if (tile < 32) { W = wn0; D = 256; nbase = 256;  local = tile - 16; }
    else if (tile < 48) { W = ws1; D = 256; nbase = 512;  local = tile - 32; }
    else if (tile < 64) { W = wn1; D = 256; nbase = 768;  local = tile - 48; }
    else if (tile < 72) { W = ws2; D = 128; nbase = 1024; local = tile - 64; }
    else                { W = wn2; D = 128; nbase = 1152; local = tile - 72; }
    if (tid == 0) wcnt = 0;
    __syncthreads();
    {
      const unsigned short* wu = (const unsigned short*)W;
      int c = 0;
#pragma unroll
      for (int r = 0; r < 2; ++r) {
        float v = bfbits2f(wu[tid + r * 256]);
        if (!(fabsf(v) < 1e6f)) c++;
      }
      if (c) atomicAdd(&wcnt, c);
    }
    __syncthreads();
    bool f32 = wcnt > 8;
    int nt = local >> 2, kt = local & 3;
    int n0 = nt * 64, k0 = kt * 64;
    int lr = tid >> 4;        // 0..15
    int lc = (tid & 15) * 4;  // 0..60
#pragma unroll
    for (int r = 0; r < 4; ++r) {
      int kl = r * 16 + lr;
      float4 v = ld4f(W, (size_t)(k0 + kl) * D + n0 + lc, f32);
      sm[lc + 0][kl] = v.x;
      sm[lc + 1][kl] = v.y;
      sm[lc + 2][kl] = v.z;
      sm[lc + 3][kl] = v.w;
    }
    __syncthreads();
#pragma unroll
    for (int r = 0; r < 4; ++r) {
      int nl = r * 16 + lr;
      ushort4 o = {f2bfbits(sm[nl][lc]), f2bfbits(sm[nl][lc + 1]),
                   f2bfbits(sm[nl][lc + 2]), f2bfbits(sm[nl][lc + 3])};
      *reinterpret_cast<ushort4*>(Bt0 + (size_t)(nbase + n0 + nl) * 256 + k0 + lc) = o;
    }
    return;
  }
  int e = (b - 81) * 256 + tid;
  if (e < NE) atomicAdd(&counts[dst[e]], 1);
}

__global__ __launch_bounds__(256) void bsum_kernel(const int* __restrict__ counts,
                                                   int* __restrict__ bsum) {
  int i = blockIdx.x * 256 + threadIdx.x;
  int v = (i < NN) ? counts[i] : 0;
#pragma unroll
  for (int off = 32; off > 0; off >>= 1) v += __shfl_down(v, off, 64);
  __shared__ int w[4];
  if ((threadIdx.x & 63) == 0) w[threadIdx.x >> 6] = v;
  __syncthreads();
  if (threadIdx.x == 0) bsum[blockIdx.x] = w[0] + w[1] + w[2] + w[3];
}

// folds bscan into rowptr — each block tree-reduces bsum[0..blockIdx).
__global__ __launch_bounds__(256) void rowptr_kernel(const int* __restrict__ counts,
                                                     const int* __restrict__ bsum,
                                                     int* __restrict__ rowptr,
                                                     int* __restrict__ cursor) {
  __shared__ int sh[256];
  int tid = threadIdx.x;
  int v0 = (tid < blockIdx.x) ? bsum[tid] : 0;  // NBLK=196 <= 256
  sh[tid] = v0;
  __syncthreads();
#pragma unroll
  for (int off = 128; off > 0; off >>= 1) {
    if (tid < off) sh[tid] += sh[tid + off];
    __syncthreads();
  }
  int base = sh[0];
  __syncthreads();
  int i = blockIdx.x * 256 + tid;
  int v = (i < NN) ? counts[i] : 0;
  sh[tid] = v;
  __syncthreads();
  for (int off = 1; off < 256; off <<= 1) {
    int t = (tid >= off) ? sh[tid - off] : 0;
    __syncthreads();
    sh[tid] += t;
    __syncthreads();
  }
  int incl = sh[tid];
  if (i < NN) {
    int r = base + incl - v;
    rowptr[i] = r;
    cursor[i] = r;
  }
  if (i == NN - 1) rowptr[NN] = base + incl;
}

// R20: single-writer-XCD fill. Block g reads edge chunk (g>>3) and fills
// only rows in range (g&7)*FRNG..+FRNG. Consecutive blockIdx round-robin
// across XCDs, so each csr_src row-segment is written by (mostly) one
// XCD -> full-line writebacks instead of 8 partial copies per line
// (R19 PMC: WRITE_SIZE 52 MB for a 3.2 MB array). dst re-read 8x is
// cheap sequential traffic. Correct under any block->XCD mapping.
__global__ void fill_kernel(const int* __restrict__ src, const int* __restrict__ dst,
                            int* __restrict__ cursor, int* __restrict__ csr_src) {
  int g = blockIdx.x;
  int range = g & 7;
  int e = (g >> 3) * 256 + threadIdx.x;
  if (e >= NE) return;
  int d = dst[e];
  if ((unsigned)(d - range * FRNG) < (unsigned)FRNG) {
    int pos = atomicAdd(&cursor[d], 1);
    csr_src[pos] = src[e];
  }
}

// ---- MFMA GEMM: Yself(bf16)=A@Ws+bias, Yn(fp8)=A@Wn ----
// Proven R17 config: BK=32, __syncthreads skeleton, coalesced LDS-restaged
// epilogue, 1-D XCD grid, fused fp32-A path for layer 0.
template <int TWO_D, bool MAYF32>
__global__ __launch_bounds__(256) void gemm_pack_kernel(
    const unsigned short* __restrict__ A0, const float* __restrict__ A1f,
    const unsigned short* __restrict__ Bt,
    const void* __restrict__ bias, unsigned short* __restrict__ Yself,
    unsigned char* __restrict__ Yn, const int* __restrict__ dtflag) {
  constexpr int D = TWO_D / 2;
  constexpr int NC = TWO_D / 128;  // col-blocks per row-panel
  __shared__ unsigned short LDS[16384];  // 32 KB; epilogue reuses all

  const int id = blockIdx.x;
  const int sup = id >> 3;
  const int rb = (id & 7) + 8 * (sup / NC);
  const int row0 = rb * 128;
  if (row0 >= NN) return;  // padded grid; block-uniform exit before barriers
  const int col0 = (sup & (NC - 1)) * 128;
  const bool self = col0 < D;  // block-uniform

  bool inf32 = dtflag[0] != 0;
  const bool af32 = MAYF32 && inf32;

  const int tid = threadIdx.x;
  const int lane = tid & 63;
  const int wave = tid >> 6;
  const int wr = (wave >> 1) * 64;
  const int wc = (wave & 1) * 64;
  const int fr = lane & 15;
  const int q = lane >> 4;
  const int sw = (q ^ ((fr >> 1) & 3)) * 8;

  floatx4 acc[4][4];
#pragma unroll
  for (int i = 0; i < 4; ++i)
#pragma unroll
    for (int j = 0; j < 4; ++j) acc[i][j] = (floatx4){0.f, 0.f, 0.f, 0.f};

  const int srow = tid >> 2;
  const int gch = ((tid & 3) ^ ((tid >> 3) & 3)) * 8;
  int ar0 = row0 + srow;      if (ar0 >= NN) ar0 = NN - 1;
  int ar1 = row0 + srow + 64; if (ar1 >= NN) ar1 = NN - 1;
  const size_t ga0 = (size_t)ar0 * 256 + gch;
  const size_t ga1 = (size_t)ar1 * 256 + gch;
  const size_t gb0 = (size_t)(col0 + srow) * 256 + gch;
  const size_t gb1 = (size_t)(col0 + srow + 64) * 256 + gch;
  const int lo0 = (tid & 192) * 8;  // wave-uniform LDS base
  unsigned short* la0 = LDS + lo0;
  unsigned short* la1 = LDS + lo0 + 2048;
  unsigned short* lb0 = LDS + 8192 + lo0;
  unsigned short* lb1 = LDS + 8192 + lo0 + 2048;

  const int arow = tid >> 3;                              // 0..31
  const int ag = ((tid & 7) ^ ((tid >> 3) & 7)) * 4;      // f32 col offset
  size_t gaf[4];
  if (MAYF32) {
#pragma unroll
    for (int m = 0; m < 4; ++m) {
      int r = row0 + 32 * m + arow;
      if (r >= NN) r = NN - 1;
      gaf[m] = (size_t)r * 256 + ag;
    }
  }

  for (int kb = 0; kb < 256; kb += 32) {
    if (kb) __syncthreads();  // WAR: all reads of prior step done
    if (af32) {
#pragma unroll
      for (int m = 0; m < 4; ++m)
        GLD_LDS16(A1f + gaf[m] + kb, LDS + m * 2048 + lo0);
    } else {
      GLD_LDS16(A0 + ga0 + kb, la0);
      GLD_LDS16(A0 + ga1 + kb, la1);
    }
    GLD_LDS16(Bt + gb0 + kb, lb0);
    GLD_LDS16(Bt + gb1 + kb, lb1);
    __syncthreads();          // full fence + vmcnt drain: staging visible
    bf16x8 af[4], bfr[4];
    if (af32) {
      const float* Af = (const float*)LDS;
#pragma unroll
      for (int i = 0; i < 4; ++i) {
        int r = wr + i * 16 + fr;
        int c0 = (q * 2) ^ (r & 7);
        float4 f0 = *reinterpret_cast<const float4*>(Af + r * 32 + c0 * 4);
        float4 f1 = *reinterpret_cast<const float4*>(Af + r * 32 + (c0 ^ 1) * 4);
        bf16x8 v;
        v[0] = (__bf16)f0.x; v[1] = (__bf16)f0.y; v[2] = (__bf16)f0.z; v[3] = (__bf16)f0.w;
        v[4] = (__bf16)f1.x; v[5] = (__bf16)f1.y; v[6] = (__bf16)f1.z; v[7] = (__bf16)f1.w;
        af[i] = v;
      }
    } else {
      const unsigned short* Ap = LDS;
#pragma unroll
      for (int i = 0; i < 4; ++i)
        af[i] = *reinterpret_cast<const bf16x8*>(Ap + (wr + i * 16 + fr) * 32 + sw);
    }
    const unsigned short* Bp = LDS + 8192;
#pragma unroll
    for (int j = 0; j < 4; ++j)
      bfr[j] = *reinterpret_cast<const bf16x8*>(Bp + (wc + j * 16 + fr) * 32 + sw);
#pragma unroll
    for (int i = 0; i < 4; ++i)
#pragma unroll
      for (int j = 0; j < 4; ++j)
        acc[i][j] = __builtin_amdgcn_mfma_f32_16x16x32_bf16(af[i], bfr[j], acc[i][j], 0, 0, 0);
  }
  __syncthreads();  // WAR: all K-loop LDS reads done before epilogue scatter

  // ---- epilogue: scatter acc -> LDS tile, then coalesced flush ----
  if (self) {
    unsigned short* T = LDS;  // [128][128] bf16, 32 KB
#pragma unroll
    for (int j = 0; j < 4; ++j) {
      int cl = wc + j * 16 + fr;  // 0..127
      float bj = ld1f(bias, col0 + cl, inf32);
#pragma unroll
      for (int i = 0; i < 4; ++i) {
        int rbase = wr + i * 16 + q * 4;
#pragma unroll
        for (int r = 0; r < 4; ++r)
          T[(rbase + r) * 128 + cl] = f2bfbits(acc[i][j][r] + bj);
      }
    }
    __syncthreads();
    const char* lp = (const char*)LDS;
    char* gp0 = (char*)Yself;
#pragma unroll
    for (int it = 0; it < 8; ++it) {
      int cb = (tid + it * 256) * 16;   // byte index in tile
      int tr = cb >> 8;                 // tile row (256 B rows)
      int cob = cb & 255;
      if (row0 + tr < NN) {
        uint4 v = *reinterpret_cast<const uint4*>(lp + cb);
        *reinterpret_cast<uint4*>(gp0 + (size_t)(row0 + tr) * (D * 2) + col0 * 2 + cob) = v;
      }
    }
  } else {
    unsigned char* T = (unsigned char*)LDS;  // [128][128] fp8, 16 KB
#pragma unroll
    for (int j = 0; j < 4; ++j) {
      int cl = wc + j * 16 + fr;
#pragma unroll
      for (int i = 0; i < 4; ++i) {
        int rbase = wr + i * 16 + q * 4;
#pragma unroll
        for (int r = 0; r < 4; ++r)
          T[(rbase + r) * 128 + cl] = f2fp8(acc[i][j][r]);
      }
    }
    __syncthreads();
    const char* lp = (const char*)LDS;
    char* gp0 = (char*)Yn;
#pragma unroll
    for (int it = 0; it < 4; ++it) {
      int cb = (tid + it * 256) * 16;
      int tr = cb >> 7;                 // tile row (128 B rows)
      int cob = cb & 127;
      if (row0 + tr < NN) {
        uint4 v = *reinterpret_cast<const uint4*>(lp + cb);
        *reinterpret_cast<uint4*>(gp0 + (size_t)(row0 + tr) * D + (col0 - D) + cob) = v;
      }
    }
  }
}

// ---- fused: h = ReLU(LN(Yself + mean(Yn[nbrs]))), D=256 ----
// At its compulsory-traffic floor (R8-R10: FETCH invariant 94MB; per-XCD
// compulsory = 8 x 63% x 12.8MB = 65MB Yn re-fetch, matches).
__global__ __launch_bounds__(256) void fused_ln_kernel(
    const unsigned char* __restrict__ Yn, const unsigned short* __restrict__ Yself,
    const int* __restrict__ rowptr, const int* __restrict__ csr_src,
    const void* __restrict__ indeg, const void* __restrict__ g,
    const void* __restrict__ be, unsigned short* __restrict__ out,
    const int* __restrict__ dtflag) {
  bool inf32 = dtflag[0] != 0;
  int row = blockIdx.x * 4 + (threadIdx.x >> 6);
  int lane = threadIdx.x & 63;
  int qq = lane >> 4;
  int l16 = lane & 15;
  int beg = rowptr[row], end = rowptr[row + 1];
  float a[16] = {};
  int e = beg + qq;
  for (; e + 4 < end; e += 8) {
    int s0 = csr_src[e], s1 = csr_src[e + 4];
    uint4 r0 = *reinterpret_cast<const uint4*>(Yn + (size_t)s0 * 256 + l16 * 16);
    uint4 r1 = *reinterpret_cast<const uint4*>(Yn + (size_t)s1 * 256 + l16 * 16);
    accf8(a, r0); accf8(a, r1);
  }
  if (e < end) {
    uint4 r0 = *reinterpret_cast<const uint4*>(Yn + (size_t)csr_src[e] * 256 + l16 * 16);
    accf8(a, r0);
  }
#pragma unroll
  for (int k = 0; k < 16; ++k) {
    a[k] += __shfl_xor(a[k], 16, 64);
    a[k] += __shfl_xor(a[k], 32, 64);
  }
  float rd = 1.0f / ld1f(indeg, row, inf32);
  uint4 ys0 = *reinterpret_cast<const uint4*>(Yself + (size_t)row * 256 + l16 * 16);
  uint4 ys1 = *reinterpret_cast<const uint4*>(Yself + (size_t)row * 256 + l16 * 16 + 8);
  const unsigned* y0 = &ys0.x;
  const unsigned* y1 = &ys1.x;
  float vals[16];
#pragma unroll
  for (int k = 0; k < 4; ++k) {
    vals[2 * k] = a[2 * k] * rd + bfbits2f((unsigned short)(y0[k] & 0xffff));
    vals[2 * k + 1] = a[2 * k + 1] * rd + bfbits2f((unsigned short)(y0[k] >> 16));
    vals[8 + 2 * k] = a[8 + 2 * k] * rd + bfbits2f((unsigned short)(y1[k] & 0xffff));
    vals[9 + 2 * k] = a[9 + 2 * k] * rd + bfbits2f((unsigned short)(y1[k] >> 16));
  }
  float s = 0.f, sq = 0.f;
#pragma unroll
  for (int k = 0; k < 16; ++k) { s += vals[k]; sq += vals[k] * vals[k]; }
#pragma unroll
  for (int off = 1; off < 16; off <<= 1) {
    s += __shfl_xor(s, off, 64);
    sq += __shfl_xor(sq, off, 64);
  }
  float mu = s * (1.0f / 256.0f);
  float var = fmaxf(sq * (1.0f / 256.0f) - mu * mu, 0.0f);
  float rs = rsqrtf(var + LN_EPS);
  if (qq == 0) {
    uint4 o0, o1;
    unsigned* u0 = &o0.x;
    unsigned* u1 = &o1.x;
#pragma unroll
    for (int k = 0; k < 4; ++k) {
      int c = l16 * 16 + 2 * k;
      float x0 = (vals[2 * k] - mu) * rs * ld1f(g, c, inf32) + ld1f(be, c, inf32);
      float x1 = (vals[2 * k + 1] - mu) * rs * ld1f(g, c + 1, inf32) + ld1f(be, c + 1, inf32);
      float x2 = (vals[8 + 2 * k] - mu) * rs * ld1f(g, c + 8, inf32) + ld1f(be, c + 8, inf32);
      float x3 = (vals[9 + 2 * k] - mu) * rs * ld1f(g, c + 9, inf32) + ld1f(be, c + 9, inf32);
      u0[k] = (unsigned)f2bfbits(fmaxf(x0, 0.f)) | ((unsigned)f2bfbits(fmaxf(x1, 0.f)) << 16);
      u1[k] = (unsigned)f2bfbits(fmaxf(x2, 0.f)) | ((unsigned)f2bfbits(fmaxf(x3, 0.f)) << 16);
    }
    *reinterpret_cast<uint4*>(out + (size_t)row * 256 + l16 * 16) = o0;
    *reinterpret_cast<uint4*>(out + (size_t)row * 256 + l16 * 16 + 8) = o1;
  }
}

// ---- fused final: d_out = Yself + mean(Yn[nbrs]); D=128 ----
__global__ __launch_bounds__(256) void fused_out_kernel(
    const unsigned char* __restrict__ Yn, const unsigned short* __restrict__ Yself,
    const int* __restrict__ rowptr, const int* __restrict__ csr_src,
    const void* __restrict__ indeg, void* __restrict__ out,
    const int* __restrict__ dtflag) {
  bool inf32 = dtflag[0] != 0;
  int row = blockIdx.x * 4 + (threadIdx.x >> 6);
  int lane = threadIdx.x & 63;
  int oo = lane >> 3;   // 0..7
  int l8 = lane & 7;
  int beg = rowptr[row], end = rowptr[row + 1];
  float a[16] = {};
  int e = beg + oo;
  for (; e + 8 < end; e += 16) {
    int s0 = csr_src[e], s1 = csr_src[e + 8];
    uint4 r0 = *reinterpret_cast<const uint4*>(Yn + (size_t)s0 * 128 + l8 * 16);
    uint4 r1 = *reinterpret_cast<const uint4*>(Yn + (size_t)s1 * 128 + l8 * 16);
    accf8(a, r0); accf8(a, r1);
  }
  if (e < end) {
    uint4 r0 = *reinterpret_cast<const uint4*>(Yn + (size_t)csr_src[e] * 128 + l8 * 16);
    accf8(a, r0);
  }
#pragma unroll
  for (int k = 0; k < 16; ++k) {
    a[k] += __shfl_xor(a[k], 8, 64);
    a[k] += __shfl_xor(a[k], 16, 64);
    a[k] += __shfl_xor(a[k], 32, 64);
  }
  if (oo == 0) {
    float rd = 1.0f / ld1f(indeg, row, inf32);
    uint4 ys0 = *reinterpret_cast<const uint4*>(Yself + (size_t)row * 128 + l8 * 16);
    uint4 ys1 = *reinterpret_cast<const uint4*>(Yself + (size_t)row * 128 + l8 * 16 + 8);
    const unsigned* y0 = &ys0.x;
    const unsigned* y1 = &ys1.x;
    float v[16];
#pragma unroll
    for (int k = 0; k < 4; ++k) {
      v[2 * k] = a[2 * k] * rd + bfbits2f((unsigned short)(y0[k] & 0xffff));
      v[2 * k + 1] = a[2 * k + 1] * rd + bfbits2f((unsigned short)(y0[k] >> 16));
      v[8 + 2 * k] = a[8 + 2 * k] * rd + bfbits2f((unsigned short)(y1[k] & 0xffff));
      v[9 + 2 * k] = a[9 + 2 * k] * rd + bfbits2f((unsigned short)(y1[k] >> 16));
    }
    size_t base = (size_t)row * 128 + l8 * 16;
    if (inf32) {
#pragma unroll
      for (int p = 0; p < 4; ++p) {
        float4 o = {v[4 * p], v[4 * p + 1], v[4 * p + 2], v[4 * p + 3]};
        *reinterpret_cast<float4*>((float*)out + base + 4 * p) = o;
      }
    } else {
      uint4 o0, o1;
      unsigned* u0 = &o0.x;
      unsigned* u1 = &o1.x;
#pragma unroll
      for (int k = 0; k < 4; ++k) {
        u0[k] = (unsigned)f2bfbits(v[2 * k]) | ((unsigned)f2bfbits(v[2 * k + 1]) << 16);
        u1[k] = (unsigned)f2bfbits(v[8 + 2 * k]) | ((unsigned)f2bfbits(v[9 + 2 * k]) << 16);
      }
      *reinterpret_cast<uint4*>((unsigned short*)out + base) = o0;
      *reinterpret_cast<uint4*>((unsigned short*)out + base + 8) = o1;
    }
  }
}

extern "C" void kernel_launch(void* const* d_in, const int* in_sizes, int n_in,
                              void* d_out, int out_size, void* d_ws, size_t ws_size,
                              hipStream_t stream) {
  const void* feat = d_in[0];
  const int* ei = (const int*)d_in[1];
  const void* indeg = d_in[2];
  const void* ws0 = d_in[3]; const void* wn0 = d_in[4]; const void* b0 = d_in[5];
  const void* ws1 = d_in[6]; const void* wn1 = d_in[7]; const void* b1 = d_in[8];
  const void* ws2 = d_in[9]; const void* wn2 = d_in[10]; const void* b2 = d_in[11];
  const void* g0 = d_in[12]; const void* be0 = d_in[13];
  const void* g1 = d_in[14]; const void* be1 = d_in[15];
  const int* src = ei;
  const int* dst = ei + NE;

  unsigned short* featbf = (unsigned short*)d_ws;            // 25.6 MB (spare)
  unsigned short* hbf = featbf + (size_t)NN * 256;           // 25.6 MB
  unsigned short* Yself = hbf + (size_t)NN * 256;            // 25.6 MB bf16 [NN][256]
  unsigned char* Yn = (unsigned char*)(Yself + (size_t)NN * 256);  // 12.8 MB fp8 [NN][256]
  unsigned short* Bt0 = (unsigned short*)(Yn + (size_t)NN * 256);
  unsigned short* Bt1 = Bt0 + 512 * 256;
  unsigned short* Bt2 = Bt1 + 512 * 256;
  int* flag = (int*)(Bt2 + 256 * 256);
  int* bsum = flag + 4;
  int* counts = bsum + 256;
  int* rowptr = counts + NN;
  int* cursor = rowptr + NN + 1;
  int* csr_src = cursor + NN;

  dim3 blk(256);
  dim3 gRow(12500);

  hipMemsetAsync(counts, 0, NN * sizeof(int), stream);
  prep_kernel<<<3206, blk, 0, stream>>>(feat, flag, ws0, wn0, ws1, wn1, ws2, wn2,
                                        Bt0, dst, counts);
  bsum_kernel<<<NBLK, blk, 0, stream>>>(counts, bsum);
  rowptr_kernel<<<NBLK, blk, 0, stream>>>(counts, bsum, rowptr, cursor);
  // single-writer-XCD fill: 8 ranges x 3125 edge chunks
  fill_kernel<<<8 * 3125, blk, 0, stream>>>(src, dst, cursor, csr_src);

  // layer 0 (fused fp32 path if flag==1)
  gemm_pack_kernel<512, true><<<dim3(392 * 4), blk, 0, stream>>>(
      (const unsigned short*)feat, (const float*)feat, Bt0, b0, Yself, Yn, flag);
  fused_ln_kernel<<<gRow, blk, 0, stream>>>(Yn, Yself, rowptr, csr_src, indeg, g0, be0, hbf, flag);
  // layer 1
  gemm_pack_kernel<512, false><<<dim3(392 * 4), blk, 0, stream>>>(
      hbf, nullptr, Bt1, b1, Yself, Yn, flag);
  fused_ln_kernel<<<gRow, blk, 0, stream>>>(Yn, Yself, rowptr, csr_src, indeg, g1, be1, hbf, flag);
  // layer 2 -> d_out
  gemm_pack_kernel<256, false><<<dim3(392 * 2), blk, 0, stream>>>(
      hbf, nullptr, Bt2, b2, Yself, Yn, flag);
  fused_out_kernel<<<gRow, blk, 0, stream>>>(Yn, Yself, rowptr, csr_src, indeg, d_out, flag);
}

// Round 14
// 446.651 us; speedup vs baseline: 1.0500x; 1.0009x over previous
//
#include <hip/hip_runtime.h>
#include <stdint.h>

#define NN 50000
#define NE 800000
#define LN_EPS 1e-5f
#define NBLK 196   // ceil(NN/256)
#define NFILL 3125 // ceil(NE/256)

typedef __attribute__((ext_vector_type(8))) __bf16 bf16x8;
typedef __attribute__((ext_vector_type(4))) float floatx4;
typedef __attribute__((ext_vector_type(2))) float floatx2;

#define GLD_LDS16(gp, lp)                                              \
  __builtin_amdgcn_global_load_lds(                                    \
      (const __attribute__((address_space(1))) unsigned int*)(gp),     \
      (__attribute__((address_space(3))) unsigned int*)(lp), 16, 0, 0)

__device__ __forceinline__ float bfbits2f(unsigned short u) {
  return __uint_as_float(((unsigned)u) << 16);
}
__device__ __forceinline__ unsigned short f2bfbits(float f) {
  unsigned u = __float_as_uint(f);
  u += 0x7FFFu + ((u >> 16) & 1u);   // round-to-nearest-even
  return (unsigned short)(u >> 16);
}
__device__ __forceinline__ unsigned char f2fp8(float f) {
  unsigned p = __builtin_amdgcn_cvt_pk_fp8_f32(f, f, 0, false);
  return (unsigned char)(p & 0xff);
}
// accumulate 16 fp8 (one uint4) into a[16] via HW cvt (2 elems/inst)
__device__ __forceinline__ void accf8(float* a, uint4 r) {
  const unsigned* u = &r.x;
#pragma unroll
  for (int k = 0; k < 4; ++k) {
    floatx2 lo = __builtin_amdgcn_cvt_pk_f32_fp8(u[k], false);
    floatx2 hi = __builtin_amdgcn_cvt_pk_f32_fp8(u[k], true);
    a[4 * k + 0] += lo[0]; a[4 * k + 1] += lo[1];
    a[4 * k + 2] += hi[0]; a[4 * k + 3] += hi[1];
  }
}
__device__ __forceinline__ float4 ld4f(const void* p, size_t i, bool f32) {
  if (f32) return *reinterpret_cast<const float4*>((const float*)p + i);
  ushort4 r = *reinterpret_cast<const ushort4*>((const unsigned short*)p + i);
  return make_float4(bfbits2f(r.x), bfbits2f(r.y), bfbits2f(r.z), bfbits2f(r.w));
}
__device__ __forceinline__ float ld1f(const void* p, size_t i, bool f32) {
  return f32 ? ((const float*)p)[i] : bfbits2f(((const unsigned short*)p)[i]);
}

// merged prep kernel.
//  block 0        : dtype detect (feat) -> flag
//  blocks 1..80   : weight transpose tiles (self-detecting dtype per-W)
//  blocks 81..3205: edge count atomics
__global__ __launch_bounds__(256) void prep_kernel(
    const void* __restrict__ feat, int* __restrict__ flag,
    const void* __restrict__ ws0, const void* __restrict__ wn0,
    const void* __restrict__ ws1, const void* __restrict__ wn1,
    const void* __restrict__ ws2, const void* __restrict__ wn2,
    unsigned short* __restrict__ Bt0,
    const int* __restrict__ dst, int* __restrict__ counts) {
  const int b = blockIdx.x;
  const int tid = threadIdx.x;
  if (b == 0) {
    if (tid < 64) {
      int cnt = 0;
      const unsigned short* u = (const unsigned short*)feat;
      for (int i = tid; i < 512; i += 64) {
        float v = bfbits2f(u[i]);
        if (!(fabsf(v) < 1e6f)) cnt++;
      }
#pragma unroll
      for (int off = 32; off > 0; off >>= 1) cnt += __shfl_down(cnt, off, 64);
      if (tid == 0) flag[0] = (cnt > 8) ? 1 : 0;
    }
    return;
  }
  if (b <= 80) {
    __shared__ float sm[64][65];
    __shared__ int wcnt;
    int tile = b - 1;  // 0..79
    const void* W;
    int D, nbase, local;
    if (tile < 16)      { W = ws0; D = 256; nbase = 0;    local = tile; }
    else if (tile < 32) { W = wn0; D = 256; nbase = 256;  local = tile - 16; }
    else if (tile < 48) { W = ws1; D = 256; nbase = 512;  local = tile - 32; }
    else if (tile < 64) { W = wn1; D = 256; nbase = 768;  local = tile - 48; }
    else if (tile < 72) { W = ws2; D = 128; nbase = 1024; local = tile - 64; }
    else                { W = wn2; D = 128; nbase = 1152; local = tile - 72; }
    if (tid == 0) wcnt = 0;
    __syncthreads();
    {
      const unsigned short* wu = (const unsigned short*)W;
      int c = 0;
#pragma unroll
      for (int r = 0; r < 2; ++r) {
        float v = bfbits2f(wu[tid + r * 256]);
        if (!(fabsf(v) < 1e6f)) c++;
      }
      if (c) atomicAdd(&wcnt, c);
    }
    __syncthreads();
    bool f32 = wcnt > 8;
    int nt = local >> 2, kt = local & 3;
    int n0 = nt * 64, k0 = kt * 64;
    int lr = tid >> 4;        // 0..15
    int lc = (tid & 15) * 4;  // 0..60
#pragma unroll
    for (int r = 0; r < 4; ++r) {
      int kl = r * 16 + lr;
      float4 v = ld4f(W, (size_t)(k0 + kl) * D + n0 + lc, f32);
      sm[lc + 0][kl] = v.x;
      sm[lc + 1][kl] = v.y;
      sm[lc + 2][kl] = v.z;
      sm[lc + 3][kl] = v.w;
    }
    __syncthreads();
#pragma unroll
    for (int r = 0; r < 4; ++r) {
      int nl = r * 16 + lr;
      ushort4 o = {f2bfbits(sm[nl][lc]), f2bfbits(sm[nl][lc + 1]),
                   f2bfbits(sm[nl][lc + 2]), f2bfbits(sm[nl][lc + 3])};
      *reinterpret_cast<ushort4*>(Bt0 + (size_t)(nbase + n0 + nl) * 256 + k0 + lc) = o;
    }
    return;
  }
  int e = (b - 81) * 256 + tid;
  if (e < NE) atomicAdd(&counts[dst[e]], 1);
}

__global__ __launch_bounds__(256) void bsum_kernel(const int* __restrict__ counts,
                                                   int* __restrict__ bsum) {
  int i = blockIdx.x * 256 + threadIdx.x;
  int v = (i < NN) ? counts[i] : 0;
#pragma unroll
  for (int off = 32; off > 0; off >>= 1) v += __shfl_down(v, off, 64);
  __shared__ int w[4];
  if ((threadIdx.x & 63) == 0) w[threadIdx.x >> 6] = v;
  __syncthreads();
  if (threadIdx.x == 0) bsum[blockIdx.x] = w[0] + w[1] + w[2] + w[3];
}

// folds bscan into rowptr — each block tree-reduces bsum[0..blockIdx).
__global__ __launch_bounds__(256) void rowptr_kernel(const int* __restrict__ counts,
                                                     const int* __restrict__ bsum,
                                                     int* __restrict__ rowptr,
                                                     int* __restrict__ cursor) {
  __shared__ int sh[256];
  int tid = threadIdx.x;
  int v0 = (tid < blockIdx.x) ? bsum[tid] : 0;  // NBLK=196 <= 256
  sh[tid] = v0;
  __syncthreads();
#pragma unroll
  for (int off = 128; off > 0; off >>= 1) {
    if (tid < off) sh[tid] += sh[tid + off];
    __syncthreads();
  }
  int base = sh[0];
  __syncthreads();
  int i = blockIdx.x * 256 + tid;
  int v = (i < NN) ? counts[i] : 0;
  sh[tid] = v;
  __syncthreads();
  for (int off = 1; off < 256; off <<= 1) {
    int t = (tid >= off) ? sh[tid - off] : 0;
    __syncthreads();
    sh[tid] += t;
    __syncthreads();
  }
  int incl = sh[tid];
  if (i < NN) {
    int r = base + incl - v;
    rowptr[i] = r;
    cursor[i] = r;
  }
  if (i == NN - 1) rowptr[NN] = base + incl;
}

// ---- MFMA GEMM: Yself(bf16)=A@Ws+bias, Yn(fp8)=A@Wn ----
// Proven R17 config: BK=32, __syncthreads skeleton, coalesced LDS-restaged
// epilogue, 1-D XCD grid, fused fp32-A path for layer 0.
// R21: layer-0's grid carries NFILL extra blocks that perform the CSR
// fill (independent of the GEMM) — fill's ~45us hides under GEMM-0
// instead of running serially. Block-range branch before any barrier,
// same proven pattern as prep_kernel.
template <int TWO_D, bool MAYF32>
__global__ __launch_bounds__(256) void gemm_pack_kernel(
    const unsigned short* __restrict__ A0, const float* __restrict__ A1f,
    const unsigned short* __restrict__ Bt,
    const void* __restrict__ bias, unsigned short* __restrict__ Yself,
    unsigned char* __restrict__ Yn, const int* __restrict__ dtflag,
    const int* __restrict__ esrc, const int* __restrict__ edst,
    int* __restrict__ cursor, int* __restrict__ csr_src) {
  constexpr int D = TWO_D / 2;
  constexpr int NC = TWO_D / 128;   // col-blocks per row-panel
  constexpr int GBLK = 392 * NC;    // gemm blocks (padded rows)
  __shared__ unsigned short LDS[16384];  // 32 KB; epilogue reuses all

  const int id = blockIdx.x;
  const int tid = threadIdx.x;
  if (MAYF32 && id >= GBLK) {
    // ---- merged CSR fill (overlaps with the GEMM blocks) ----
    int e = (id - GBLK) * 256 + tid;
    if (e < NE) {
      int pos = atomicAdd(&cursor[edst[e]], 1);
      csr_src[pos] = esrc[e];
    }
    return;
  }
  const int sup = id >> 3;
  const int rb = (id & 7) + 8 * (sup / NC);
  const int row0 = rb * 128;
  if (row0 >= NN) return;  // padded grid; block-uniform exit before barriers
  const int col0 = (sup & (NC - 1)) * 128;
  const bool self = col0 < D;  // block-uniform

  bool inf32 = dtflag[0] != 0;
  const bool af32 = MAYF32 && inf32;

  const int lane = tid & 63;
  const int wave = tid >> 6;
  const int wr = (wave >> 1) * 64;
  const int wc = (wave & 1) * 64;
  const int fr = lane & 15;
  const int q = lane >> 4;
  const int sw = (q ^ ((fr >> 1) & 3)) * 8;

  floatx4 acc[4][4];
#pragma unroll
  for (int i = 0; i < 4; ++i)
#pragma unroll
    for (int j = 0; j < 4; ++j) acc[i][j] = (floatx4){0.f, 0.f, 0.f, 0.f};

  const int srow = tid >> 2;
  const int gch = ((tid & 3) ^ ((tid >> 3) & 3)) * 8;
  int ar0 = row0 + srow;      if (ar0 >= NN) ar0 = NN - 1;
  int ar1 = row0 + srow + 64; if (ar1 >= NN) ar1 = NN - 1;
  const size_t ga0 = (size_t)ar0 * 256 + gch;
  const size_t ga1 = (size_t)ar1 * 256 + gch;
  const size_t gb0 = (size_t)(col0 + srow) * 256 + gch;
  const size_t gb1 = (size_t)(col0 + srow + 64) * 256 + gch;
  const int lo0 = (tid & 192) * 8;  // wave-uniform LDS base
  unsigned short* la0 = LDS + lo0;
  unsigned short* la1 = LDS + lo0 + 2048;
  unsigned short* lb0 = LDS + 8192 + lo0;
  unsigned short* lb1 = LDS + 8192 + lo0 + 2048;

  const int arow = tid >> 3;                              // 0..31
  const int ag = ((tid & 7) ^ ((tid >> 3) & 7)) * 4;      // f32 col offset
  size_t gaf[4];
  if (MAYF32) {
#pragma unroll
    for (int m = 0; m < 4; ++m) {
      int r = row0 + 32 * m + arow;
      if (r >= NN) r = NN - 1;
      gaf[m] = (size_t)r * 256 + ag;
    }
  }

  for (int kb = 0; kb < 256; kb += 32) {
    if (kb) __syncthreads();  // WAR: all reads of prior step done
    if (af32) {
#pragma unroll
      for (int m = 0; m < 4; ++m)
        GLD_LDS16(A1f + gaf[m] + kb, LDS + m * 2048 + lo0);
    } else {
      GLD_LDS16(A0 + ga0 + kb, la0);
      GLD_LDS16(A0 + ga1 + kb, la1);
    }
    GLD_LDS16(Bt + gb0 + kb, lb0);
    GLD_LDS16(Bt + gb1 + kb, lb1);
    __syncthreads();          // full fence + vmcnt drain: staging visible
    bf16x8 af[4], bfr[4];
    if (af32) {
      const float* Af = (const float*)LDS;
#pragma unroll
      for (int i = 0; i < 4; ++i) {
        int r = wr + i * 16 + fr;
        int c0 = (q * 2) ^ (r & 7);
        float4 f0 = *reinterpret_cast<const float4*>(Af + r * 32 + c0 * 4);
        float4 f1 = *reinterpret_cast<const float4*>(Af + r * 32 + (c0 ^ 1) * 4);
        bf16x8 v;
        v[0] = (__bf16)f0.x; v[1] = (__bf16)f0.y; v[2] = (__bf16)f0.z; v[3] = (__bf16)f0.w;
        v[4] = (__bf16)f1.x; v[5] = (__bf16)f1.y; v[6] = (__bf16)f1.z; v[7] = (__bf16)f1.w;
        af[i] = v;
      }
    } else {
      const unsigned short* Ap = LDS;
#pragma unroll
      for (int i = 0; i < 4; ++i)
        af[i] = *reinterpret_cast<const bf16x8*>(Ap + (wr + i * 16 + fr) * 32 + sw);
    }
    const unsigned short* Bp = LDS + 8192;
#pragma unroll
    for (int j = 0; j < 4; ++j)
      bfr[j] = *reinterpret_cast<const bf16x8*>(Bp + (wc + j * 16 + fr) * 32 + sw);
#pragma unroll
    for (int i = 0; i < 4; ++i)
#pragma unroll
      for (int j = 0; j < 4; ++j)
        acc[i][j] = __builtin_amdgcn_mfma_f32_16x16x32_bf16(af[i], bfr[j], acc[i][j], 0, 0, 0);
  }
  __syncthreads();  // WAR: all K-loop LDS reads done before epilogue scatter

  // ---- epilogue: scatter acc -> LDS tile, then coalesced flush ----
  if (self) {
    unsigned short* T = LDS;  // [128][128] bf16, 32 KB
#pragma unroll
    for (int j = 0; j < 4; ++j) {
      int cl = wc + j * 16 + fr;  // 0..127
      float bj = ld1f(bias, col0 + cl, inf32);
#pragma unroll
      for (int i = 0; i < 4; ++i) {
        int rbase = wr + i * 16 + q * 4;
#pragma unroll
        for (int r = 0; r < 4; ++r)
          T[(rbase + r) * 128 + cl] = f2bfbits(acc[i][j][r] + bj);
      }
    }
    __syncthreads();
    const char* lp = (const char*)LDS;
    char* gp0 = (char*)Yself;
#pragma unroll
    for (int it = 0; it < 8; ++it) {
      int cb = (tid + it * 256) * 16;   // byte index in tile
      int tr = cb >> 8;                 // tile row (256 B rows)
      int cob = cb & 255;
      if (row0 + tr < NN) {
        uint4 v = *reinterpret_cast<const uint4*>(lp + cb);
        *reinterpret_cast<uint4*>(gp0 + (size_t)(row0 + tr) * (D * 2) + col0 * 2 + cob) = v;
      }
    }
  } else {
    unsigned char* T = (unsigned char*)LDS;  // [128][128] fp8, 16 KB
#pragma unroll
    for (int j = 0; j < 4; ++j) {
      int cl = wc + j * 16 + fr;
#pragma unroll
      for (int i = 0; i < 4; ++i) {
        int rbase = wr + i * 16 + q * 4;
#pragma unroll
        for (int r = 0; r < 4; ++r)
          T[(rbase + r) * 128 + cl] = f2fp8(acc[i][j][r]);
      }
    }
    __syncthreads();
    const char* lp = (const char*)LDS;
    char* gp0 = (char*)Yn;
#pragma unroll
    for (int it = 0; it < 4; ++it) {
      int cb = (tid + it * 256) * 16;
      int tr = cb >> 7;                 // tile row (128 B rows)
      int cob = cb & 127;
      if (row0 + tr < NN) {
        uint4 v = *reinterpret_cast<const uint4*>(lp + cb);
        *reinterpret_cast<uint4*>(gp0 + (size_t)(row0 + tr) * D + (col0 - D) + cob) = v;
      }
    }
  }
}

// ---- fused: h = ReLU(LN(Yself + mean(Yn[nbrs]))), D=256 ----
// At its compulsory-traffic floor (R8-R10: FETCH invariant 94MB; per-XCD
// compulsory = 8 x 63% x 12.8MB = 65MB Yn re-fetch, matches).
__global__ __launch_bounds__(256) void fused_ln_kernel(
    const unsigned char* __restrict__ Yn, const unsigned short* __restrict__ Yself,
    const int* __restrict__ rowptr, const int* __restrict__ csr_src,
    const void* __restrict__ indeg, const void* __restrict__ g,
    const void* __restrict__ be, unsigned short* __restrict__ out,
    const int* __restrict__ dtflag) {
  bool inf32 = dtflag[0] != 0;
  int row = blockIdx.x * 4 + (threadIdx.x >> 6);
  int lane = threadIdx.x & 63;
  int qq = lane >> 4;
  int l16 = lane & 15;
  int beg = rowptr[row], end = rowptr[row + 1];
  float a[16] = {};
  int e = beg + qq;
  for (; e + 4 < end; e += 8) {
    int s0 = csr_src[e], s1 = csr_src[e + 4];
    uint4 r0 = *reinterpret_cast<const uint4*>(Yn + (size_t)s0 * 256 + l16 * 16);
    uint4 r1 = *reinterpret_cast<const uint4*>(Yn + (size_t)s1 * 256 + l16 * 16);
    accf8(a, r0); accf8(a, r1);
  }
  if (e < end) {
    uint4 r0 = *reinterpret_cast<const uint4*>(Yn + (size_t)csr_src[e] * 256 + l16 * 16);
    accf8(a, r0);
  }
#pragma unroll
  for (int k = 0; k < 16; ++k) {
    a[k] += __shfl_xor(a[k], 16, 64);
    a[k] += __shfl_xor(a[k], 32, 64);
  }
  float rd = 1.0f / ld1f(indeg, row, inf32);
  uint4 ys0 = *reinterpret_cast<const uint4*>(Yself + (size_t)row * 256 + l16 * 16);
  uint4 ys1 = *reinterpret_cast<const uint4*>(Yself + (size_t)row * 256 + l16 * 16 + 8);
  const unsigned* y0 = &ys0.x;
  const unsigned* y1 = &ys1.x;
  float vals[16];
#pragma unroll
  for (int k = 0; k < 4; ++k) {
    vals[2 * k] = a[2 * k] * rd + bfbits2f((unsigned short)(y0[k] & 0xffff));
    vals[2 * k + 1] = a[2 * k + 1] * rd + bfbits2f((unsigned short)(y0[k] >> 16));
    vals[8 + 2 * k] = a[8 + 2 * k] * rd + bfbits2f((unsigned short)(y1[k] & 0xffff));
    vals[9 + 2 * k] = a[9 + 2 * k] * rd + bfbits2f((unsigned short)(y1[k] >> 16));
  }
  float s = 0.f, sq = 0.f;
#pragma unroll
  for (int k = 0; k < 16; ++k) { s += vals[k]; sq += vals[k] * vals[k]; }
#pragma unroll
  for (int off = 1; off < 16; off <<= 1) {
    s += __shfl_xor(s, off, 64);
    sq += __shfl_xor(sq, off, 64);
  }
  float mu = s * (1.0f / 256.0f);
  float var = fmaxf(sq * (1.0f / 256.0f) - mu * mu, 0.0f);
  float rs = rsqrtf(var + LN_EPS);
  if (qq == 0) {
    uint4 o0, o1;
    unsigned* u0 = &o0.x;
    unsigned* u1 = &o1.x;
#pragma unroll
    for (int k = 0; k < 4; ++k) {
      int c = l16 * 16 + 2 * k;
      float x0 = (vals[2 * k] - mu) * rs * ld1f(g, c, inf32) + ld1f(be, c, inf32);
      float x1 = (vals[2 * k + 1] - mu) * rs * ld1f(g, c + 1, inf32) + ld1f(be, c + 1, inf32);
      float x2 = (vals[8 + 2 * k] - mu) * rs * ld1f(g, c + 8, inf32) + ld1f(be, c + 8, inf32);
      float x3 = (vals[9 + 2 * k] - mu) * rs * ld1f(g, c + 9, inf32) + ld1f(be, c + 9, inf32);
      u0[k] = (unsigned)f2bfbits(fmaxf(x0, 0.f)) | ((unsigned)f2bfbits(fmaxf(x1, 0.f)) << 16);
      u1[k] = (unsigned)f2bfbits(fmaxf(x2, 0.f)) | ((unsigned)f2bfbits(fmaxf(x3, 0.f)) << 16);
    }
    *reinterpret_cast<uint4*>(out + (size_t)row * 256 + l16 * 16) = o0;
    *reinterpret_cast<uint4*>(out + (size_t)row * 256 + l16 * 16 + 8) = o1;
  }
}

// ---- fused final: d_out = Yself + mean(Yn[nbrs]); D=128 ----
__global__ __launch_bounds__(256) void fused_out_kernel(
    const unsigned char* __restrict__ Yn, const unsigned short* __restrict__ Yself,
    const int* __restrict__ rowptr, const int* __restrict__ csr_src,
    const void* __restrict__ indeg, void* __restrict__ out,
    const int* __restrict__ dtflag) {
  bool inf32 = dtflag[0] != 0;
  int row = blockIdx.x * 4 + (threadIdx.x >> 6);
  int lane = threadIdx.x & 63;
  int oo = lane >> 3;   // 0..7
  int l8 = lane & 7;
  int beg = rowptr[row], end = rowptr[row + 1];
  float a[16] = {};
  int e = beg + oo;
  for (; e + 8 < end; e += 16) {
    int s0 = csr_src[e], s1 = csr_src[e + 8];
    uint4 r0 = *reinterpret_cast<const uint4*>(Yn + (size_t)s0 * 128 + l8 * 16);
    uint4 r1 = *reinterpret_cast<const uint4*>(Yn + (size_t)s1 * 128 + l8 * 16);
    accf8(a, r0); accf8(a, r1);
  }
  if (e < end) {
    uint4 r0 = *reinterpret_cast<const uint4*>(Yn + (size_t)csr_src[e] * 128 + l8 * 16);
    accf8(a, r0);
  }
#pragma unroll
  for (int k = 0; k < 16; ++k) {
    a[k] += __shfl_xor(a[k], 8, 64);
    a[k] += __shfl_xor(a[k], 16, 64);
    a[k] += __shfl_xor(a[k], 32, 64);
  }
  if (oo == 0) {
    float rd = 1.0f / ld1f(indeg, row, inf32);
    uint4 ys0 = *reinterpret_cast<const uint4*>(Yself + (size_t)row * 128 + l8 * 16);
    uint4 ys1 = *reinterpret_cast<const uint4*>(Yself + (size_t)row * 128 + l8 * 16 + 8);
    const unsigned* y0 = &ys0.x;
    const unsigned* y1 = &ys1.x;
    float v[16];
#pragma unroll
    for (int k = 0; k < 4; ++k) {
      v[2 * k] = a[2 * k] * rd + bfbits2f((unsigned short)(y0[k] & 0xffff));
      v[2 * k + 1] = a[2 * k + 1] * rd + bfbits2f((unsigned short)(y0[k] >> 16));
      v[8 + 2 * k] = a[8 + 2 * k] * rd + bfbits2f((unsigned short)(y1[k] & 0xffff));
      v[9 + 2 * k] = a[9 + 2 * k] * rd + bfbits2f((unsigned short)(y1[k] >> 16));
    }
    size_t base = (size_t)row * 128 + l8 * 16;
    if (inf32) {
#pragma unroll
      for (int p = 0; p < 4; ++p) {
        float4 o = {v[4 * p], v[4 * p + 1], v[4 * p + 2], v[4 * p + 3]};
        *reinterpret_cast<float4*>((float*)out + base + 4 * p) = o;
      }
    } else {
      uint4 o0, o1;
      unsigned* u0 = &o0.x;
      unsigned* u1 = &o1.x;
#pragma unroll
      for (int k = 0; k < 4; ++k) {
        u0[k] = (unsigned)f2bfbits(v[2 * k]) | ((unsigned)f2bfbits(v[2 * k + 1]) << 16);
        u1[k] = (unsigned)f2bfbits(v[8 + 2 * k]) | ((unsigned)f2bfbits(v[9 + 2 * k]) << 16);
      }
      *reinterpret_cast<uint4*>((unsigned short*)out + base) = o0;
      *reinterpret_cast<uint4*>((unsigned short*)out + base + 8) = o1;
    }
  }
}

extern "C" void kernel_launch(void* const* d_in, const int* in_sizes, int n_in,
                              void* d_out, int out_size, void* d_ws, size_t ws_size,
                              hipStream_t stream) {
  const void* feat = d_in[0];
  const int* ei = (const int*)d_in[1];
  const void* indeg = d_in[2];
  const void* ws0 = d_in[3]; const void* wn0 = d_in[4]; const void* b0 = d_in[5];
  const void* ws1 = d_in[6]; const void* wn1 = d_in[7]; const void* b1 = d_in[8];
  const void* ws2 = d_in[9]; const void* wn2 = d_in[10]; const void* b2 = d_in[11];
  const void* g0 = d_in[12]; const void* be0 = d_in[13];
  const void* g1 = d_in[14]; const void* be1 = d_in[15];
  const int* src = ei;
  const int* dst = ei + NE;

  unsigned short* featbf = (unsigned short*)d_ws;            // 25.6 MB (spare)
  unsigned short* hbf = featbf + (size_t)NN * 256;           // 25.6 MB
  unsigned short* Yself = hbf + (size_t)NN * 256;            // 25.6 MB bf16 [NN][256]
  unsigned char* Yn = (unsigned char*)(Yself + (size_t)NN * 256);  // 12.8 MB fp8 [NN][256]
  unsigned short* Bt0 = (unsigned short*)(Yn + (size_t)NN * 256);
  unsigned short* Bt1 = Bt0 + 512 * 256;
  unsigned short* Bt2 = Bt1 + 512 * 256;
  int* flag = (int*)(Bt2 + 256 * 256);
  int* bsum = flag + 4;
  int* counts = bsum + 256;
  int* rowptr = counts + NN;
  int* cursor = rowptr + NN + 1;
  int* csr_src = cursor + NN;

  dim3 blk(256);
  dim3 gRow(12500);

  hipMemsetAsync(counts, 0, NN * sizeof(int), stream);
  prep_kernel<<<3206, blk, 0, stream>>>(feat, flag, ws0, wn0, ws1, wn1, ws2, wn2,
                                        Bt0, dst, counts);
  bsum_kernel<<<NBLK, blk, 0, stream>>>(counts, bsum);
  rowptr_kernel<<<NBLK, blk, 0, stream>>>(counts, bsum, rowptr, cursor);

  // layer 0 GEMM + merged CSR fill (fill blocks overlap the GEMM)
  gemm_pack_kernel<512, true><<<dim3(392 * 4 + NFILL), blk, 0, stream>>>(
      (const unsigned short*)feat, (const float*)feat, Bt0, b0, Yself, Yn, flag,
      src, dst, cursor, csr_src);
  fused_ln_kernel<<<gRow, blk, 0, stream>>>(Yn, Yself, rowptr, csr_src, indeg, g0, be0, hbf, flag);
  // layer 1
  gemm_pack_kernel<512, false><<<dim3(392 * 4), blk, 0, stream>>>(
      hbf, nullptr, Bt1, b1, Yself, Yn, flag, nullptr, nullptr, nullptr, nullptr);
  fused_ln_kernel<<<gRow, blk, 0, stream>>>(Yn, Yself, rowptr, csr_src, indeg, g1, be1, hbf, flag);
  // layer 2 -> d_out
  gemm_pack_kernel<256, false><<<dim3(392 * 2), blk, 0, stream>>>(
      hbf, nullptr, Bt2, b2, Yself, Yn, flag, nullptr, nullptr, nullptr, nullptr);
  fused_out_kernel<<<gRow, blk, 0, stream>>>(Yn, Yself, rowptr, csr_src, indeg, d_out, flag);
}